// Round 1
// baseline (416.222 us; speedup 1.0000x reference)
//
#include <hip/hip_runtime.h>

#define V_TOTAL 8192
#define C_DIM   64
#define N_TOK   32768
#define TM      128      // tokens per block tile
#define TV      128      // codes per LDS chunk
#define VSPLIT  2
#define VSEG    (V_TOTAL / VSPLIT)   // 4096
#define CHUNKS  (VSEG / TV)          // 32

// ws layout (float offsets):
//   wnT      [64][8192]       @ 0        (2 MiB)  normalized codes, transposed
//   bestval  [VSPLIT][32768]  @ 524288
//   bestidx  [VSPLIT][32768]  @ 589824   (int)
//   counts   [8192]           @ 655360   (int)
//   blocksq  [128]            @ 663552

__global__ __launch_bounds__(256)
void k_prep(const float* __restrict__ w, float* __restrict__ wnT,
            int* __restrict__ counts) {
    int v = blockIdx.x * 256 + threadIdx.x;   // 8192 threads, one code each
    counts[v] = 0;
    const float4* row = (const float4*)(w + v * C_DIM);
    float4 r[16];
    float s = 0.f;
#pragma unroll
    for (int i = 0; i < 16; ++i) {
        r[i] = row[i];
        s += r[i].x * r[i].x + r[i].y * r[i].y + r[i].z * r[i].z + r[i].w * r[i].w;
    }
    float nrm = fmaxf(sqrtf(s), 1e-12f);
#pragma unroll
    for (int i = 0; i < 16; ++i) {
        wnT[(i * 4 + 0) * V_TOTAL + v] = r[i].x / nrm;
        wnT[(i * 4 + 1) * V_TOTAL + v] = r[i].y / nrm;
        wnT[(i * 4 + 2) * V_TOTAL + v] = r[i].z / nrm;
        wnT[(i * 4 + 3) * V_TOTAL + v] = r[i].w / nrm;
    }
}

__global__ __launch_bounds__(256)
void k_argmax(const float* __restrict__ f, const float* __restrict__ wnT,
              float* __restrict__ bestval, int* __restrict__ bestidx) {
    __shared__ float sA[C_DIM * TM];   // [k][token] 32 KB
    __shared__ float sB[C_DIM * TV];   // [k][code]  32 KB

    const int tid   = threadIdx.x;
    const int tile  = blockIdx.x;      // 0..255
    const int split = blockIdx.y;      // 0..VSPLIT-1
    const int t0    = tile * TM;
    const int bb    = t0 >> 10;        // batch index (1024 tokens per b)
    const int hw0   = t0 & 1023;
    const float* fbase = f + bb * 65536 + hw0;

    // stage token tile, k-major, fully coalesced
#pragma unroll
    for (int q = 0; q < 8; ++q) {
        int id = q * 256 + tid;
        int c = id >> 5, p = (id & 31) * 4;
        float4 val = *(const float4*)(fbase + c * 1024 + p);
        *(float4*)(sA + c * TM + p) = val;
    }

    const int tc = tid & 15;
    const int tr = tid >> 4;

    float best[8];
    int   bidx[8];
#pragma unroll
    for (int i = 0; i < 8; ++i) { best[i] = -3.4e38f; bidx[i] = 0; }

    for (int ch = 0; ch < CHUNKS; ++ch) {
        const int vbase = split * VSEG + ch * TV;
        __syncthreads();   // previous chunk's reads done (also covers sA staging)
#pragma unroll
        for (int q = 0; q < 8; ++q) {
            int id = q * 256 + tid;
            int c = id >> 5, p = (id & 31) * 4;
            float4 val = *(const float4*)(wnT + c * V_TOTAL + vbase + p);
            *(float4*)(sB + c * TV + p) = val;
        }
        __syncthreads();

        float acc[8][8];
#pragma unroll
        for (int i = 0; i < 8; ++i)
#pragma unroll
            for (int j = 0; j < 8; ++j) acc[i][j] = 0.f;

#pragma unroll 4
        for (int k = 0; k < C_DIM; ++k) {
            float4 a0 = *(const float4*)(sA + k * TM + tr * 8);
            float4 a1 = *(const float4*)(sA + k * TM + tr * 8 + 4);
            float4 b0 = *(const float4*)(sB + k * TV + tc * 4);        // codes tc*4..+3
            float4 b1 = *(const float4*)(sB + k * TV + 64 + tc * 4);   // codes 64+tc*4..+3
            float av[8] = {a0.x, a0.y, a0.z, a0.w, a1.x, a1.y, a1.z, a1.w};
            float bv[8] = {b0.x, b0.y, b0.z, b0.w, b1.x, b1.y, b1.z, b1.w};
#pragma unroll
            for (int i = 0; i < 8; ++i)
#pragma unroll
                for (int j = 0; j < 8; ++j)
                    acc[i][j] = fmaf(av[i], bv[j], acc[i][j]);
        }

#pragma unroll
        for (int j = 0; j < 8; ++j) {
            int code = vbase + ((j < 4) ? (tc * 4 + j) : (64 + tc * 4 + (j - 4)));
#pragma unroll
            for (int i = 0; i < 8; ++i) {
                if (acc[i][j] > best[i]) { best[i] = acc[i][j]; bidx[i] = code; }
            }
        }
    }

    // cross-thread (tc) argmax reduce per token, via LDS (reuse sA/sB)
    __syncthreads();
    float* sv = sA;          // [16][TM]
    int*   si = (int*)sB;    // [16][TM]
#pragma unroll
    for (int i = 0; i < 8; ++i) {
        sv[tc * TM + tr * 8 + i] = best[i];
        si[tc * TM + tr * 8 + i] = bidx[i];
    }
    __syncthreads();
    if (tid < TM) {
        float bv = sv[tid];
        int   bi = si[tid];
#pragma unroll
        for (int c = 1; c < 16; ++c) {
            float v = sv[c * TM + tid];
            int  ix = si[c * TM + tid];
            if (v > bv || (v == bv && ix < bi)) { bv = v; bi = ix; }
        }
        bestval[split * N_TOK + t0 + tid] = bv;
        bestidx[split * N_TOK + t0 + tid] = bi;
    }
}

__global__ __launch_bounds__(256)
void k_finalize(const float* __restrict__ f, const float* __restrict__ w,
                const float* __restrict__ bestval, const int* __restrict__ bestidx,
                int* __restrict__ counts, float* __restrict__ blocksq,
                float* __restrict__ out) {
    const int tid = threadIdx.x;
    const int t   = blockIdx.x * 256 + tid;   // token id

    float v0 = bestval[t],        v1 = bestval[N_TOK + t];
    int   i0 = bestidx[t],        i1 = bestidx[N_TOK + t];
    int idx = (v1 > v0 || (v1 == v0 && i1 < i0)) ? i1 : i0;
    atomicAdd(&counts[idx], 1);

    float4 cr[16];
    const float4* crow = (const float4*)(w + idx * C_DIM);
#pragma unroll
    for (int i = 0; i < 16; ++i) cr[i] = crow[i];
    const float* crs = (const float*)cr;

    const int bb = t >> 10;
    const int hw = t & 1023;
    const float* fb = f + bb * 65536 + hw;
    float*       ob = out + bb * 65536 + hw;

    float s = 0.f;
#pragma unroll
    for (int c = 0; c < C_DIM; ++c) {
        float fv = fb[c * 1024];
        float fh = crs[c];
        float d  = fh - fv;
        s += d * d;
        ob[c * 1024] = fv + d;   // f + sg(fhat - f), same arithmetic as ref
    }

    __shared__ float red[256];
    red[tid] = s;
    __syncthreads();
    for (int st = 128; st > 0; st >>= 1) {
        if (tid < st) red[tid] += red[tid + st];
        __syncthreads();
    }
    if (tid == 0) blocksq[blockIdx.x] = red[0];
}

__global__ __launch_bounds__(256)
void k_stats(const int* __restrict__ counts, const float* __restrict__ blocksq,
             float* __restrict__ out) {
    __shared__ float redf[256];
    __shared__ int   redi[256];
    const int tid = threadIdx.x;
    int used = 0;
    for (int v = tid; v < V_TOTAL; v += 256) used += (counts[v] > 0) ? 1 : 0;
    redi[tid] = used;
    redf[tid] = (tid < 128) ? blocksq[tid] : 0.f;
    __syncthreads();
    for (int st = 128; st > 0; st >>= 1) {
        if (tid < st) { redi[tid] += redi[tid + st]; redf[tid] += redf[tid + st]; }
        __syncthreads();
    }
    if (tid == 0) {
        float mse = redf[0] / 2097152.0f;
        out[2097152] = 0.25f * mse + mse;   // BETA*mean + mean
        out[2097153] = 0.0f;                // entropy_loss
        out[2097154] = 100.0f * (float)redi[0] / 8192.0f;  // vocab_usage
    }
}

extern "C" void kernel_launch(void* const* d_in, const int* in_sizes, int n_in,
                              void* d_out, int out_size, void* d_ws, size_t ws_size,
                              hipStream_t stream) {
    const float* f = (const float*)d_in[0];
    const float* w = (const float*)d_in[1];
    float* out = (float*)d_out;
    float* ws  = (float*)d_ws;

    float* wnT     = ws;
    float* bestval = ws + 524288;
    int*   bestidx = (int*)(ws + 589824);
    int*   counts  = (int*)(ws + 655360);
    float* blocksq = ws + 663552;

    hipLaunchKernelGGL(k_prep, dim3(32), dim3(256), 0, stream, w, wnT, counts);
    hipLaunchKernelGGL(k_argmax, dim3(256, VSPLIT), dim3(256), 0, stream,
                       f, wnT, bestval, bestidx);
    hipLaunchKernelGGL(k_finalize, dim3(128), dim3(256), 0, stream,
                       f, w, bestval, bestidx, counts, blocksq, out);
    hipLaunchKernelGGL(k_stats, dim3(1), dim3(256), 0, stream,
                       counts, blocksq, out);
}

// Round 2
// 127.841 us; speedup vs baseline: 3.2558x; 3.2558x over previous
//
#include <hip/hip_runtime.h>

typedef _Float16 f16x8 __attribute__((ext_vector_type(8)));
typedef float f32x16 __attribute__((ext_vector_type(16)));

#define V_TOTAL 8192
#define C_DIM   64
#define N_TOK   32768
#define VSPLIT  4
#define VSEG    (V_TOTAL / VSPLIT)   // 2048
#define CHUNKS  (VSEG / 32)          // 64
#define INV2048 4.8828125e-4f

#define Z16 {0.f,0.f,0.f,0.f,0.f,0.f,0.f,0.f,0.f,0.f,0.f,0.f,0.f,0.f,0.f,0.f}

// ws float offsets:
//   cp       f16[1048576] @ 0        (2 MiB) packed split codes
//            layout: halves offset = ((CV*2+T)*8+q)*256 + c*8,  CV=v>>5, c=v&31,
//            granule q holds k = q*8..q*8+7   (k-slot mapping cancels A vs B)
//   bestval  [4][32768]   @ 524288
//   bestidx  [4][32768]   @ 655360   (int)
//   counts   [8192]       @ 786432   (int)
//   blocksq  [128]        @ 794624

__global__ __launch_bounds__(256)
void k_prep(const float* __restrict__ w, _Float16* __restrict__ cp,
            int* __restrict__ counts) {
    int v = blockIdx.x * 256 + threadIdx.x;   // one code per thread
    counts[v] = 0;
    const float4* row = (const float4*)(w + v * C_DIM);
    float4 r[16];
    float s = 0.f;
#pragma unroll
    for (int i = 0; i < 16; ++i) {
        r[i] = row[i];
        s += r[i].x * r[i].x + r[i].y * r[i].y + r[i].z * r[i].z + r[i].w * r[i].w;
    }
    float inv = 1.0f / fmaxf(sqrtf(s), 1e-12f);
    const float* rs = (const float*)r;
    const int cv = v >> 5, c = v & 31;
#pragma unroll
    for (int q = 0; q < 8; ++q) {
        f16x8 hi, lo;
#pragma unroll
        for (int j = 0; j < 8; ++j) {
            float x = rs[q * 8 + j] * inv;
            _Float16 h = (_Float16)x;
            hi[j] = h;
            lo[j] = (_Float16)((x - (float)h) * 2048.0f);
        }
        *(f16x8*)(cp + ((cv * 2 + 0) * 8 + q) * 256 + c * 8) = hi;
        *(f16x8*)(cp + ((cv * 2 + 1) * 8 + q) * 256 + c * 8) = lo;
    }
}

__global__ __launch_bounds__(64, 2)
void k_argmax(const float* __restrict__ f, const _Float16* __restrict__ cp,
              float* __restrict__ bestval, int* __restrict__ bestidx) {
    const int lane = threadIdx.x;        // 0..63
    const int c31  = lane & 31;
    const int g    = lane >> 5;
    const int seg  = blockIdx.y;         // 0..3
    const int t0   = blockIdx.x * 64;    // 64 tokens per wave

    // ---- B (token) fragments, held in registers for the whole kernel ----
    // frag halves j for K-step ks map to channel k = ks*16 + g*8 + j
    f16x8 bh[2][4], bl[2][4];
#pragma unroll
    for (int tg = 0; tg < 2; ++tg) {
        const int T = t0 + tg * 32 + c31;
        const float* fb = f + (T >> 10) * 65536 + (T & 1023);
#pragma unroll
        for (int ks = 0; ks < 4; ++ks) {
#pragma unroll
            for (int j = 0; j < 8; ++j) {
                float v = fb[(ks * 16 + g * 8 + j) * 1024];
                _Float16 h = (_Float16)v;
                bh[tg][ks][j] = h;
                bl[tg][ks][j] = (_Float16)((v - (float)h) * 2048.0f);
            }
        }
    }

    // per-lane A-frag base: chunk-local frag = cA + cv*4096 + term*2048 + ks*512
    const _Float16* cA = cp + seg * (CHUNKS * 4096) + g * 256 + c31 * 8;

    float best0 = -3.4e38f, best1 = -3.4e38f;
    int   bidx0 = 0,        bidx1 = 0;

    f16x8 Ah0[4], Al0[4], Ah1[4], Al1[4];

    auto ldchunk = [&](f16x8 (&AH)[4], f16x8 (&AL)[4], int cv) {
#pragma unroll
        for (int ks = 0; ks < 4; ++ks) {
            AH[ks] = *(const f16x8*)(cA + cv * 4096 + ks * 512);
            AL[ks] = *(const f16x8*)(cA + cv * 4096 + 2048 + ks * 512);
        }
    };

    auto compute = [&](const f16x8 (&AH)[4], const f16x8 (&AL)[4], int codebase) {
        f32x16 a00 = Z16, a01 = Z16, a10 = Z16, a11 = Z16;
#pragma unroll
        for (int ks = 0; ks < 4; ++ks) {
            a00 = __builtin_amdgcn_mfma_f32_32x32x16_f16(AH[ks], bh[0][ks], a00, 0, 0, 0);
            a10 = __builtin_amdgcn_mfma_f32_32x32x16_f16(AH[ks], bh[1][ks], a10, 0, 0, 0);
            a01 = __builtin_amdgcn_mfma_f32_32x32x16_f16(AH[ks], bl[0][ks], a01, 0, 0, 0);
            a11 = __builtin_amdgcn_mfma_f32_32x32x16_f16(AH[ks], bl[1][ks], a11, 0, 0, 0);
            a01 = __builtin_amdgcn_mfma_f32_32x32x16_f16(AL[ks], bh[0][ks], a01, 0, 0, 0);
            a11 = __builtin_amdgcn_mfma_f32_32x32x16_f16(AL[ks], bh[1][ks], a11, 0, 0, 0);
        }
        const int base = codebase + 4 * g;
        // C/D layout (m74/m101): col = lane&31 (token), row = (r&3)+8*(r>>2)+4*g
        // rows ascend with r for fixed lane -> strict '>' keeps smallest code on ties
#pragma unroll
        for (int r = 0; r < 16; ++r) {
            const int code = base + (r & 3) + 8 * (r >> 2);
            float s0 = fmaf(a01[r], INV2048, a00[r]);
            bool u0 = s0 > best0;
            best0 = u0 ? s0 : best0;
            bidx0 = u0 ? code : bidx0;
            float s1 = fmaf(a11[r], INV2048, a10[r]);
            bool u1 = s1 > best1;
            best1 = u1 ? s1 : best1;
            bidx1 = u1 ? code : bidx1;
        }
    };

    ldchunk(Ah0, Al0, 0);
    for (int cv = 0; cv < CHUNKS; cv += 2) {
        ldchunk(Ah1, Al1, cv + 1);
        compute(Ah0, Al0, seg * VSEG + cv * 32);
        if (cv + 2 < CHUNKS) ldchunk(Ah0, Al0, cv + 2);
        compute(Ah1, Al1, seg * VSEG + (cv + 1) * 32);
    }

    // merge the two lane-halves (g=0 holds codes ..+0..3, g=1 holds ..+4..7)
    {
        float ov = __shfl_xor(best0, 32);
        int   oi = __shfl_xor(bidx0, 32);
        if (ov > best0 || (ov == best0 && oi < bidx0)) { best0 = ov; bidx0 = oi; }
        ov = __shfl_xor(best1, 32);
        oi = __shfl_xor(bidx1, 32);
        if (ov > best1 || (ov == best1 && oi < bidx1)) { best1 = ov; bidx1 = oi; }
    }
    if (lane < 32) {
        bestval[seg * N_TOK + t0 + c31]      = best0;
        bestidx[seg * N_TOK + t0 + c31]      = bidx0;
        bestval[seg * N_TOK + t0 + 32 + c31] = best1;
        bestidx[seg * N_TOK + t0 + 32 + c31] = bidx1;
    }
}

__global__ __launch_bounds__(256)
void k_finalize(const float* __restrict__ f, const float* __restrict__ w,
                const float* __restrict__ bestval, const int* __restrict__ bestidx,
                int* __restrict__ counts, float* __restrict__ blocksq,
                float* __restrict__ out) {
    const int tid = threadIdx.x;
    const int t   = blockIdx.x * 256 + tid;   // token id

    float bv = bestval[t];
    int   bi = bestidx[t];
#pragma unroll
    for (int s = 1; s < VSPLIT; ++s) {
        float v  = bestval[s * N_TOK + t];
        int   ix = bestidx[s * N_TOK + t];
        if (v > bv || (v == bv && ix < bi)) { bv = v; bi = ix; }
    }
    atomicAdd(&counts[bi], 1);

    float4 cr[16];
    const float4* crow = (const float4*)(w + bi * C_DIM);
#pragma unroll
    for (int i = 0; i < 16; ++i) cr[i] = crow[i];
    const float* crs = (const float*)cr;

    const int bb = t >> 10;
    const int hw = t & 1023;
    const float* fb = f + bb * 65536 + hw;
    float*       ob = out + bb * 65536 + hw;

    float s = 0.f;
#pragma unroll
    for (int c = 0; c < C_DIM; ++c) {
        float fv = fb[c * 1024];
        float fh = crs[c];
        float d  = fh - fv;
        s += d * d;
        ob[c * 1024] = fv + d;   // f + sg(fhat - f)
    }

    __shared__ float red[256];
    red[tid] = s;
    __syncthreads();
    for (int st = 128; st > 0; st >>= 1) {
        if (tid < st) red[tid] += red[tid + st];
        __syncthreads();
    }
    if (tid == 0) blocksq[blockIdx.x] = red[0];
}

__global__ __launch_bounds__(256)
void k_stats(const int* __restrict__ counts, const float* __restrict__ blocksq,
             float* __restrict__ out) {
    __shared__ float redf[256];
    __shared__ int   redi[256];
    const int tid = threadIdx.x;
    int used = 0;
    for (int v = tid; v < V_TOTAL; v += 256) used += (counts[v] > 0) ? 1 : 0;
    redi[tid] = used;
    redf[tid] = (tid < 128) ? blocksq[tid] : 0.f;
    __syncthreads();
    for (int st = 128; st > 0; st >>= 1) {
        if (tid < st) { redi[tid] += redi[tid + st]; redf[tid] += redf[tid + st]; }
        __syncthreads();
    }
    if (tid == 0) {
        float mse = redf[0] / 2097152.0f;
        out[2097152] = 0.25f * mse + mse;   // BETA*mean + mean
        out[2097153] = 0.0f;                // entropy_loss
        out[2097154] = 100.0f * (float)redi[0] / 8192.0f;  // vocab_usage
    }
}

extern "C" void kernel_launch(void* const* d_in, const int* in_sizes, int n_in,
                              void* d_out, int out_size, void* d_ws, size_t ws_size,
                              hipStream_t stream) {
    const float* f = (const float*)d_in[0];
    const float* w = (const float*)d_in[1];
    float* out = (float*)d_out;
    float* ws  = (float*)d_ws;

    _Float16* cp      = (_Float16*)ws;
    float*    bestval = ws + 524288;
    int*      bestidx = (int*)(ws + 655360);
    int*      counts  = (int*)(ws + 786432);
    float*    blocksq = ws + 794624;

    hipLaunchKernelGGL(k_prep, dim3(32), dim3(256), 0, stream, w, cp, counts);
    hipLaunchKernelGGL(k_argmax, dim3(512, VSPLIT), dim3(64), 0, stream,
                       f, cp, bestval, bestidx);
    hipLaunchKernelGGL(k_finalize, dim3(128), dim3(256), 0, stream,
                       f, w, bestval, bestidx, counts, blocksq, out);
    hipLaunchKernelGGL(k_stats, dim3(1), dim3(256), 0, stream,
                       counts, blocksq, out);
}

// Round 3
// 126.435 us; speedup vs baseline: 3.2920x; 1.0111x over previous
//
#include <hip/hip_runtime.h>

typedef _Float16 f16x8 __attribute__((ext_vector_type(8)));
typedef float f32x16 __attribute__((ext_vector_type(16)));

#define V_TOTAL 8192
#define C_DIM   64
#define N_TOK   32768
#define VSPLIT  4
#define VSEG    (V_TOTAL / VSPLIT)   // 2048
#define CHUNKS  (VSEG / 32)          // 64
#define INV2048 4.8828125e-4f

// ws float offsets:
//   cp      f16[1048576]  @ 0        (2 MiB) packed split codes
//           halves offset = cv*4096 + term*2048 + q*256 + c*8   (k = q*8+j)
//   keys    u64[32768]    @ 524288   (256 KiB) packed (sortable_sim, 8191-idx)
//   counts  int[8192]     @ 589824
//   blocksq f32[128]      @ 598016

__device__ __forceinline__ unsigned long long packkey(float s, int idx) {
    unsigned u = __float_as_uint(s);
    unsigned k = u ^ ((unsigned)(((int)u) >> 31) | 0x80000000u);
    return ((unsigned long long)k << 32) | (unsigned)(8191 - idx);
}

__global__ __launch_bounds__(256)
void k_prep(const float* __restrict__ w, _Float16* __restrict__ cp,
            unsigned long long* __restrict__ keys, int* __restrict__ counts) {
    int v = blockIdx.x * 256 + threadIdx.x;   // one code per thread
    counts[v] = 0;
#pragma unroll
    for (int i = 0; i < 4; ++i) keys[v * 4 + i] = 0ull;   // 8192*4 = 32768
    const float4* row = (const float4*)(w + v * C_DIM);
    float4 r[16];
    float s = 0.f;
#pragma unroll
    for (int i = 0; i < 16; ++i) {
        r[i] = row[i];
        s += r[i].x * r[i].x + r[i].y * r[i].y + r[i].z * r[i].z + r[i].w * r[i].w;
    }
    float inv = 1.0f / fmaxf(sqrtf(s), 1e-12f);
    const float* rs = (const float*)r;
    const int cv = v >> 5, c = v & 31;
#pragma unroll
    for (int q = 0; q < 8; ++q) {
        f16x8 hi, lo;
#pragma unroll
        for (int j = 0; j < 8; ++j) {
            float x = rs[q * 8 + j] * inv;
            _Float16 h = (_Float16)x;
            hi[j] = h;
            lo[j] = (_Float16)((x - (float)h) * 2048.0f);
        }
        *(f16x8*)(cp + cv * 4096 +        q * 256 + c * 8) = hi;
        *(f16x8*)(cp + cv * 4096 + 2048 + q * 256 + c * 8) = lo;
    }
}

__global__ __launch_bounds__(64, 2)
void k_argmax(const float* __restrict__ f, const _Float16* __restrict__ cp,
              unsigned long long* __restrict__ keys) {
    const int lane = threadIdx.x;        // 0..63
    const int c31  = lane & 31;
    const int g    = lane >> 5;
    const int seg  = blockIdx.y;         // 0..VSPLIT-1
    const int t0   = blockIdx.x * 64;    // 64 tokens per wave

    // ---- B (token) fragments, register-resident ----
    f16x8 bh[2][4], bl[2][4];
#pragma unroll
    for (int tg = 0; tg < 2; ++tg) {
        const int T = t0 + tg * 32 + c31;
        const float* fb = f + (T >> 10) * 65536 + (T & 1023);
#pragma unroll
        for (int ks = 0; ks < 4; ++ks) {
#pragma unroll
            for (int j = 0; j < 8; ++j) {
                float v = fb[(ks * 16 + g * 8 + j) * 1024];
                _Float16 h = (_Float16)v;
                bh[tg][ks][j] = h;
                bl[tg][ks][j] = (_Float16)((v - (float)h) * 2048.0f);
            }
        }
    }

    const _Float16* cA = cp + seg * (CHUNKS * 4096) + g * 256 + c31 * 8;

    f32x16 zacc = {0.f,0.f,0.f,0.f,0.f,0.f,0.f,0.f,0.f,0.f,0.f,0.f,0.f,0.f,0.f,0.f};

    float best0 = -3.4e38f, best1 = -3.4e38f;
    int   bidx0 = 0,        bidx1 = 0;   // hold code' (without +4g), added at end

    f16x8 AHa[4], ALa[4], AHb[4], ALb[4];

    auto ldchunk = [&](f16x8 (&AH)[4], f16x8 (&AL)[4], int cv) {
#pragma unroll
        for (int ks = 0; ks < 4; ++ks) {
            AH[ks] = *(const f16x8*)(cA + cv * 4096 + ks * 512);
            AL[ks] = *(const f16x8*)(cA + cv * 4096 + 2048 + ks * 512);
        }
    };

    auto compute = [&](const f16x8 (&AH)[4], const f16x8 (&AL)[4], int cv) {
        f32x16 a00, a01, a10, a11;
        a00 = __builtin_amdgcn_mfma_f32_32x32x16_f16(AH[0], bh[0][0], zacc, 0, 0, 0);
        a01 = __builtin_amdgcn_mfma_f32_32x32x16_f16(AH[0], bl[0][0], zacc, 0, 0, 0);
        a10 = __builtin_amdgcn_mfma_f32_32x32x16_f16(AH[0], bh[1][0], zacc, 0, 0, 0);
        a11 = __builtin_amdgcn_mfma_f32_32x32x16_f16(AH[0], bl[1][0], zacc, 0, 0, 0);
        a01 = __builtin_amdgcn_mfma_f32_32x32x16_f16(AL[0], bh[0][0], a01, 0, 0, 0);
        a11 = __builtin_amdgcn_mfma_f32_32x32x16_f16(AL[0], bh[1][0], a11, 0, 0, 0);
#pragma unroll
        for (int ks = 1; ks < 4; ++ks) {
            a00 = __builtin_amdgcn_mfma_f32_32x32x16_f16(AH[ks], bh[0][ks], a00, 0, 0, 0);
            a01 = __builtin_amdgcn_mfma_f32_32x32x16_f16(AH[ks], bl[0][ks], a01, 0, 0, 0);
            a10 = __builtin_amdgcn_mfma_f32_32x32x16_f16(AH[ks], bh[1][ks], a10, 0, 0, 0);
            a11 = __builtin_amdgcn_mfma_f32_32x32x16_f16(AH[ks], bl[1][ks], a11, 0, 0, 0);
            a01 = __builtin_amdgcn_mfma_f32_32x32x16_f16(AL[ks], bh[0][ks], a01, 0, 0, 0);
            a11 = __builtin_amdgcn_mfma_f32_32x32x16_f16(AL[ks], bh[1][ks], a11, 0, 0, 0);
        }
        const int codebase = seg * VSEG + cv * 32;   // wave-uniform (SGPR)
#pragma unroll
        for (int r = 0; r < 16; ++r) {
            const int codeq = codebase + (r & 3) + 8 * (r >> 2);  // scalar
            float s0 = fmaf(a01[r], INV2048, a00[r]);
            bool u0 = s0 > best0;
            best0 = u0 ? s0 : best0;
            bidx0 = u0 ? codeq : bidx0;
            float s1 = fmaf(a11[r], INV2048, a10[r]);
            bool u1 = s1 > best1;
            best1 = u1 ? s1 : best1;
            bidx1 = u1 ? codeq : bidx1;
        }
    };

    ldchunk(AHa, ALa, 0);
    for (int cv = 0; cv < CHUNKS; cv += 2) {
        ldchunk(AHb, ALb, cv + 1);
        compute(AHa, ALa, cv);
        if (cv + 2 < CHUNKS) ldchunk(AHa, ALa, cv + 2);
        compute(AHb, ALb, cv + 1);
    }

    bidx0 += 4 * g;
    bidx1 += 4 * g;
    {
        float ov = __shfl_xor(best0, 32);
        int   oi = __shfl_xor(bidx0, 32);
        if (ov > best0 || (ov == best0 && oi < bidx0)) { best0 = ov; bidx0 = oi; }
        ov = __shfl_xor(best1, 32);
        oi = __shfl_xor(bidx1, 32);
        if (ov > best1 || (ov == best1 && oi < bidx1)) { best1 = ov; bidx1 = oi; }
    }
    if (lane < 32) {
        atomicMax(&keys[t0 + c31],      packkey(best0, bidx0));
        atomicMax(&keys[t0 + 32 + c31], packkey(best1, bidx1));
    }
}

__global__ __launch_bounds__(256)
void k_finalize(const float* __restrict__ f, const float* __restrict__ w,
                const unsigned long long* __restrict__ keys,
                int* __restrict__ counts, float* __restrict__ blocksq,
                float* __restrict__ out) {
    const int tid = threadIdx.x;
    const int t   = blockIdx.x * 256 + tid;   // token id

    const int bi = 8191 - (int)(unsigned)(keys[t] & 0xFFFFFFFFull);
    atomicAdd(&counts[bi], 1);

    float4 cr[16];
    const float4* crow = (const float4*)(w + bi * C_DIM);
#pragma unroll
    for (int i = 0; i < 16; ++i) cr[i] = crow[i];
    const float* crs = (const float*)cr;

    const int bb = t >> 10;
    const int hw = t & 1023;
    const float* fb = f + bb * 65536 + hw;
    float*       ob = out + bb * 65536 + hw;

    float s = 0.f;
#pragma unroll
    for (int c = 0; c < C_DIM; ++c) {
        float fv = fb[c * 1024];
        float fh = crs[c];
        float d  = fh - fv;
        s += d * d;
        ob[c * 1024] = fv + d;   // f + sg(fhat - f)
    }

    __shared__ float red[256];
    red[tid] = s;
    __syncthreads();
    for (int st = 128; st > 0; st >>= 1) {
        if (tid < st) red[tid] += red[tid + st];
        __syncthreads();
    }
    if (tid == 0) blocksq[blockIdx.x] = red[0];
}

__global__ __launch_bounds__(256)
void k_stats(const int* __restrict__ counts, const float* __restrict__ blocksq,
             float* __restrict__ out) {
    __shared__ float redf[256];
    __shared__ int   redi[256];
    const int tid = threadIdx.x;
    int used = 0;
    for (int v = tid; v < V_TOTAL; v += 256) used += (counts[v] > 0) ? 1 : 0;
    redi[tid] = used;
    redf[tid] = (tid < 128) ? blocksq[tid] : 0.f;
    __syncthreads();
    for (int st = 128; st > 0; st >>= 1) {
        if (tid < st) { redi[tid] += redi[tid + st]; redf[tid] += redf[tid + st]; }
        __syncthreads();
    }
    if (tid == 0) {
        float mse = redf[0] / 2097152.0f;
        out[2097152] = 0.25f * mse + mse;   // BETA*mean + mean
        out[2097153] = 0.0f;                // entropy_loss
        out[2097154] = 100.0f * (float)redi[0] / 8192.0f;  // vocab_usage
    }
}

extern "C" void kernel_launch(void* const* d_in, const int* in_sizes, int n_in,
                              void* d_out, int out_size, void* d_ws, size_t ws_size,
                              hipStream_t stream) {
    const float* f = (const float*)d_in[0];
    const float* w = (const float*)d_in[1];
    float* out = (float*)d_out;
    float* ws  = (float*)d_ws;

    _Float16*           cp      = (_Float16*)ws;
    unsigned long long* keys    = (unsigned long long*)(ws + 524288);
    int*                counts  = (int*)(ws + 589824);
    float*              blocksq = ws + 598016;

    hipLaunchKernelGGL(k_prep, dim3(32), dim3(256), 0, stream, w, cp, keys, counts);
    hipLaunchKernelGGL(k_argmax, dim3(512, VSPLIT), dim3(64), 0, stream,
                       f, cp, keys);
    hipLaunchKernelGGL(k_finalize, dim3(128), dim3(256), 0, stream,
                       f, w, keys, counts, blocksq, out);
    hipLaunchKernelGGL(k_stats, dim3(1), dim3(256), 0, stream,
                       counts, blocksq, out);
}

// Round 4
// 123.388 us; speedup vs baseline: 3.3733x; 1.0247x over previous
//
#include <hip/hip_runtime.h>

typedef _Float16 f16x8 __attribute__((ext_vector_type(8)));
typedef float f32x16 __attribute__((ext_vector_type(16)));

#define V_TOTAL 8192
#define C_DIM   64
#define N_TOK   32768
#define VSPLIT  4
#define VSEG    (V_TOTAL / VSPLIT)   // 2048
#define CHUNKS  (VSEG / 32)          // 64
#define INV2048 4.8828125e-4f

typedef const __attribute__((address_space(1))) _Float16 glb_f16;
typedef __attribute__((address_space(3))) _Float16 lds_f16;

// ws float offsets:
//   cp      f16[1048576]  @ 0        (2 MiB) packed split codes
//           halves offset = cv*4096 + term*2048 + q*256 + c*8   (k = q*8+j)
//   keys    u64[32768]    @ 524288   (256 KiB) packed (sortable_sim, 8191-idx)
//   counts  int[8192]     @ 589824
//   blocksq f32[128]      @ 598016

__device__ __forceinline__ unsigned long long packkey(float s, int idx) {
    unsigned u = __float_as_uint(s);
    unsigned k = u ^ ((unsigned)(((int)u) >> 31) | 0x80000000u);
    return ((unsigned long long)k << 32) | (unsigned)(8191 - idx);
}

__global__ __launch_bounds__(256)
void k_prep(const float* __restrict__ w, _Float16* __restrict__ cp,
            unsigned long long* __restrict__ keys, int* __restrict__ counts) {
    int v = blockIdx.x * 256 + threadIdx.x;   // one code per thread
    counts[v] = 0;
#pragma unroll
    for (int i = 0; i < 4; ++i) keys[v * 4 + i] = 0ull;   // 8192*4 = 32768
    const float4* row = (const float4*)(w + v * C_DIM);
    float4 r[16];
    float s = 0.f;
#pragma unroll
    for (int i = 0; i < 16; ++i) {
        r[i] = row[i];
        s += r[i].x * r[i].x + r[i].y * r[i].y + r[i].z * r[i].z + r[i].w * r[i].w;
    }
    float inv = 1.0f / fmaxf(sqrtf(s), 1e-12f);
    const float* rs = (const float*)r;
    const int cv = v >> 5, c = v & 31;
#pragma unroll
    for (int q = 0; q < 8; ++q) {
        f16x8 hi, lo;
#pragma unroll
        for (int j = 0; j < 8; ++j) {
            float x = rs[q * 8 + j] * inv;
            _Float16 h = (_Float16)x;
            hi[j] = h;
            lo[j] = (_Float16)((x - (float)h) * 2048.0f);
        }
        *(f16x8*)(cp + cv * 4096 +        q * 256 + c * 8) = hi;
        *(f16x8*)(cp + cv * 4096 + 2048 + q * 256 + c * 8) = lo;
    }
}

// 4 waves/block; each wave owns 32 tokens; block shares the staged code chunks.
__global__ __launch_bounds__(256, 4)
void k_argmax(const float* __restrict__ f, const _Float16* __restrict__ cp,
              unsigned long long* __restrict__ keys) {
    __shared__ __align__(16) _Float16 lds[2][4096];   // 2 x 8 KiB chunk buffers

    const int tid  = threadIdx.x;
    const int lane = tid & 63;
    const int wid  = tid >> 6;
    const int c31  = lane & 31;
    const int g    = lane >> 5;
    const int seg  = blockIdx.y;          // 0..VSPLIT-1
    const int t0   = blockIdx.x * 128 + wid * 32;   // this wave's 32 tokens

    // ---- B (token) fragments, register-resident: 8 x f16x8 = 32 VGPR ----
    f16x8 bh[4], bl[4];
    {
        const int T = t0 + c31;
        const float* fb = f + (T >> 10) * 65536 + (T & 1023);
#pragma unroll
        for (int ks = 0; ks < 4; ++ks) {
#pragma unroll
            for (int j = 0; j < 8; ++j) {
                float v = fb[(ks * 16 + g * 8 + j) * 1024];
                _Float16 h = (_Float16)v;
                bh[ks][j] = h;
                bl[ks][j] = (_Float16)((v - (float)h) * 2048.0f);
            }
        }
    }

    const _Float16* seg_cp = cp + (size_t)seg * (CHUNKS * 4096);

    // stage chunk cv into lds[buf]: 8 KiB, each wave covers 2 KiB linearly
    auto stage = [&](int cv, int buf) {
        const _Float16* src = seg_cp + cv * 4096 + wid * 1024 + lane * 8;
        _Float16* dst = &lds[buf][wid * 1024];    // wave-uniform base
        __builtin_amdgcn_global_load_lds((glb_f16*)src,       (lds_f16*)dst,       16, 0, 0);
        __builtin_amdgcn_global_load_lds((glb_f16*)(src+512), (lds_f16*)(dst+512), 16, 0, 0);
    };

    f32x16 am = {0.f,0.f,0.f,0.f,0.f,0.f,0.f,0.f,0.f,0.f,0.f,0.f,0.f,0.f,0.f,0.f};
    f32x16 ac = am;

    float best = -3.4e38f;
    int   bidx = 0;    // holds code' (without +4g), added at end

    stage(0, 0);
    __syncthreads();

    for (int cv = 0; cv < CHUNKS; ++cv) {
        if (cv + 1 < CHUNKS) stage(cv + 1, (cv + 1) & 1);

        const _Float16* base = &lds[cv & 1][g * 256 + c31 * 8];
#pragma unroll
        for (int ks = 0; ks < 4; ++ks) {
            f16x8 AH = *(const f16x8*)(base + ks * 512);
            f16x8 AL = *(const f16x8*)(base + 2048 + ks * 512);
            am = __builtin_amdgcn_mfma_f32_32x32x16_f16(AH, bh[ks], am, 0, 0, 0);
            ac = __builtin_amdgcn_mfma_f32_32x32x16_f16(AH, bl[ks], ac, 0, 0, 0);
            ac = __builtin_amdgcn_mfma_f32_32x32x16_f16(AL, bh[ks], ac, 0, 0, 0);
        }

        const int codebase = seg * VSEG + cv * 32;   // wave-uniform
#pragma unroll
        for (int r = 0; r < 16; ++r) {
            const int codeq = codebase + (r & 3) + 8 * (r >> 2);
            float s = fmaf(ac[r], INV2048, am[r]);
            bool u = s > best;
            best = u ? s : best;
            bidx = u ? codeq : bidx;
            am[r] = 0.f;
            ac[r] = 0.f;
        }
        __syncthreads();
    }

    bidx += 4 * g;
    {
        float ov = __shfl_xor(best, 32);
        int   oi = __shfl_xor(bidx, 32);
        if (ov > best || (ov == best && oi < bidx)) { best = ov; bidx = oi; }
    }
    if (lane < 32) {
        atomicMax(&keys[t0 + c31], packkey(best, bidx));
    }
}

__global__ __launch_bounds__(256)
void k_finalize(const float* __restrict__ f, const float* __restrict__ w,
                const unsigned long long* __restrict__ keys,
                int* __restrict__ counts, float* __restrict__ blocksq,
                float* __restrict__ out) {
    const int tid = threadIdx.x;
    const int t   = blockIdx.x * 256 + tid;   // token id

    const int bi = 8191 - (int)(unsigned)(keys[t] & 0xFFFFFFFFull);
    atomicAdd(&counts[bi], 1);

    float4 cr[16];
    const float4* crow = (const float4*)(w + bi * C_DIM);
#pragma unroll
    for (int i = 0; i < 16; ++i) cr[i] = crow[i];
    const float* crs = (const float*)cr;

    const int bb = t >> 10;
    const int hw = t & 1023;
    const float* fb = f + bb * 65536 + hw;
    float*       ob = out + bb * 65536 + hw;

    float s = 0.f;
#pragma unroll
    for (int c = 0; c < C_DIM; ++c) {
        float fv = fb[c * 1024];
        float fh = crs[c];
        float d  = fh - fv;
        s += d * d;
        ob[c * 1024] = fv + d;   // f + sg(fhat - f)
    }

    __shared__ float red[256];
    red[tid] = s;
    __syncthreads();
    for (int st = 128; st > 0; st >>= 1) {
        if (tid < st) red[tid] += red[tid + st];
        __syncthreads();
    }
    if (tid == 0) blocksq[blockIdx.x] = red[0];
}

__global__ __launch_bounds__(256)
void k_stats(const int* __restrict__ counts, const float* __restrict__ blocksq,
             float* __restrict__ out) {
    __shared__ float redf[256];
    __shared__ int   redi[256];
    const int tid = threadIdx.x;
    int used = 0;
    for (int v = tid; v < V_TOTAL; v += 256) used += (counts[v] > 0) ? 1 : 0;
    redi[tid] = used;
    redf[tid] = (tid < 128) ? blocksq[tid] : 0.f;
    __syncthreads();
    for (int st = 128; st > 0; st >>= 1) {
        if (tid < st) { redi[tid] += redi[tid + st]; redf[tid] += redf[tid + st]; }
        __syncthreads();
    }
    if (tid == 0) {
        float mse = redf[0] / 2097152.0f;
        out[2097152] = 0.25f * mse + mse;   // BETA*mean + mean
        out[2097153] = 0.0f;                // entropy_loss
        out[2097154] = 100.0f * (float)redi[0] / 8192.0f;  // vocab_usage
    }
}

extern "C" void kernel_launch(void* const* d_in, const int* in_sizes, int n_in,
                              void* d_out, int out_size, void* d_ws, size_t ws_size,
                              hipStream_t stream) {
    const float* f = (const float*)d_in[0];
    const float* w = (const float*)d_in[1];
    float* out = (float*)d_out;
    float* ws  = (float*)d_ws;

    _Float16*           cp      = (_Float16*)ws;
    unsigned long long* keys    = (unsigned long long*)(ws + 524288);
    int*                counts  = (int*)(ws + 589824);
    float*              blocksq = ws + 598016;

    hipLaunchKernelGGL(k_prep, dim3(32), dim3(256), 0, stream, w, cp, keys, counts);
    hipLaunchKernelGGL(k_argmax, dim3(N_TOK / 128, VSPLIT), dim3(256), 0, stream,
                       f, cp, keys);
    hipLaunchKernelGGL(k_finalize, dim3(128), dim3(256), 0, stream,
                       f, w, keys, counts, blocksq, out);
    hipLaunchKernelGGL(k_stats, dim3(1), dim3(256), 0, stream,
                       counts, blocksq, out);
}

// Round 5
// 121.139 us; speedup vs baseline: 3.4359x; 1.0186x over previous
//
#include <hip/hip_runtime.h>

typedef _Float16 f16x8 __attribute__((ext_vector_type(8)));
typedef float f32x16 __attribute__((ext_vector_type(16)));

#define V_TOTAL 8192
#define C_DIM   64
#define N_TOK   32768
#define VSPLIT  8
#define VSEG    (V_TOTAL / VSPLIT)   // 1024
#define CHUNKS  (VSEG / 32)          // 32
#define INV2048 4.8828125e-4f

typedef const __attribute__((address_space(1))) _Float16 glb_f16;
typedef __attribute__((address_space(3))) _Float16 lds_f16;

// ws float offsets:
//   cp      f16[1048576]  @ 0        (2 MiB) packed split codes
//           offset = cvg*4096 + term*2048 + q*256 + c*8   (k = q*8+j, cvg = global chunk)
//   keys    u64[32768]    @ 524288   (256 KiB) packed (sortable_sim, 8191-idx)
//   counts  int[8192]     @ 589824
//   blocksq f32[256]      @ 598016

__device__ __forceinline__ unsigned long long packkey(float s, int idx) {
    unsigned u = __float_as_uint(s);
    unsigned k = u ^ ((unsigned)(((int)u) >> 31) | 0x80000000u);
    return ((unsigned long long)k << 32) | (unsigned)(8191 - idx);
}

__global__ __launch_bounds__(256)
void k_prep(const float* __restrict__ w, _Float16* __restrict__ cp,
            unsigned long long* __restrict__ keys, int* __restrict__ counts) {
    int v = blockIdx.x * 256 + threadIdx.x;   // one code per thread
    counts[v] = 0;
#pragma unroll
    for (int i = 0; i < 4; ++i) keys[v * 4 + i] = 0ull;   // 8192*4 = 32768
    const float4* row = (const float4*)(w + v * C_DIM);
    float4 r[16];
    float s = 0.f;
#pragma unroll
    for (int i = 0; i < 16; ++i) {
        r[i] = row[i];
        s += r[i].x * r[i].x + r[i].y * r[i].y + r[i].z * r[i].z + r[i].w * r[i].w;
    }
    float inv = 1.0f / fmaxf(sqrtf(s), 1e-12f);
    const float* rs = (const float*)r;
    const int cv = v >> 5, c = v & 31;
#pragma unroll
    for (int q = 0; q < 8; ++q) {
        f16x8 hi, lo;
#pragma unroll
        for (int j = 0; j < 8; ++j) {
            float x = rs[q * 8 + j] * inv;
            _Float16 h = (_Float16)x;
            hi[j] = h;
            lo[j] = (_Float16)((x - (float)h) * 2048.0f);
        }
        *(f16x8*)(cp + cv * 4096 +        q * 256 + c * 8) = hi;
        *(f16x8*)(cp + cv * 4096 + 2048 + q * 256 + c * 8) = lo;
    }
}

// 4 waves/block; each wave owns 32 tokens; block shares staged code chunks via LDS.
__global__ __launch_bounds__(256, 4)
void k_argmax(const float* __restrict__ f, const _Float16* __restrict__ cp,
              unsigned long long* __restrict__ keys) {
    __shared__ __align__(16) _Float16 lds[2][4096];   // 2 x 8 KiB chunk buffers

    const int tid  = threadIdx.x;
    const int lane = tid & 63;
    const int wid  = tid >> 6;
    const int c31  = lane & 31;
    const int g    = lane >> 5;
    const int seg  = blockIdx.y;          // 0..VSPLIT-1
    const int t0   = blockIdx.x * 128 + wid * 32;   // this wave's 32 tokens

    // ---- B (token) fragments, register-resident: 8 x f16x8 = 32 VGPR ----
    f16x8 bh[4], bl[4];
    {
        const int T = t0 + c31;
        const float* fb = f + (T >> 10) * 65536 + (T & 1023);
#pragma unroll
        for (int ks = 0; ks < 4; ++ks) {
#pragma unroll
            for (int j = 0; j < 8; ++j) {
                float v = fb[(ks * 16 + g * 8 + j) * 1024];
                _Float16 h = (_Float16)v;
                bh[ks][j] = h;
                bl[ks][j] = (_Float16)((v - (float)h) * 2048.0f);
            }
        }
    }

    const _Float16* seg_cp = cp + (size_t)seg * (CHUNKS * 4096);

    // stage chunk cv into lds[buf]: 8 KiB, each wave covers 2 KiB linearly
    auto stage = [&](int cv, int buf) {
        const _Float16* src = seg_cp + cv * 4096 + wid * 1024 + lane * 8;
        _Float16* dst = &lds[buf][wid * 1024];    // wave-uniform base
        __builtin_amdgcn_global_load_lds((glb_f16*)src,       (lds_f16*)dst,       16, 0, 0);
        __builtin_amdgcn_global_load_lds((glb_f16*)(src+512), (lds_f16*)(dst+512), 16, 0, 0);
    };

    const f32x16 zacc = {0.f,0.f,0.f,0.f,0.f,0.f,0.f,0.f,0.f,0.f,0.f,0.f,0.f,0.f,0.f,0.f};

    float best = -3.4e38f;
    int   bidx = 0;    // holds code' (without +4g), added at end

    stage(0, 0);
    __syncthreads();

#pragma unroll 2
    for (int cv = 0; cv < CHUNKS; ++cv) {
        if (cv + 1 < CHUNKS) stage(cv + 1, (cv + 1) & 1);

        const _Float16* base = &lds[cv & 1][g * 256 + c31 * 8];
        f32x16 am, ac;
        {
            f16x8 AH = *(const f16x8*)(base);
            f16x8 AL = *(const f16x8*)(base + 2048);
            am = __builtin_amdgcn_mfma_f32_32x32x16_f16(AH, bh[0], zacc, 0, 0, 0);
            ac = __builtin_amdgcn_mfma_f32_32x32x16_f16(AH, bl[0], zacc, 0, 0, 0);
            ac = __builtin_amdgcn_mfma_f32_32x32x16_f16(AL, bh[0], ac, 0, 0, 0);
        }
#pragma unroll
        for (int ks = 1; ks < 4; ++ks) {
            f16x8 AH = *(const f16x8*)(base + ks * 512);
            f16x8 AL = *(const f16x8*)(base + 2048 + ks * 512);
            am = __builtin_amdgcn_mfma_f32_32x32x16_f16(AH, bh[ks], am, 0, 0, 0);
            ac = __builtin_amdgcn_mfma_f32_32x32x16_f16(AH, bl[ks], ac, 0, 0, 0);
            ac = __builtin_amdgcn_mfma_f32_32x32x16_f16(AL, bh[ks], ac, 0, 0, 0);
        }

        const int codebase = seg * VSEG + cv * 32;   // wave-uniform (SGPR)
#pragma unroll
        for (int r = 0; r < 16; ++r) {
            const int codeq = codebase + (r & 3) + 8 * (r >> 2);
            float s = fmaf(ac[r], INV2048, am[r]);
            bool u = s > best;
            best = u ? s : best;
            bidx = u ? codeq : bidx;
        }
        __syncthreads();
    }

    bidx += 4 * g;
    {
        float ov = __shfl_xor(best, 32);
        int   oi = __shfl_xor(bidx, 32);
        if (ov > best || (ov == best && oi < bidx)) { best = ov; bidx = oi; }
    }
    if (lane < 32) {
        atomicMax(&keys[t0 + c31], packkey(best, bidx));
    }
}

__global__ __launch_bounds__(128)
void k_finalize(const float* __restrict__ f, const float* __restrict__ w,
                const unsigned long long* __restrict__ keys,
                int* __restrict__ counts, float* __restrict__ blocksq,
                float* __restrict__ out) {
    const int tid = threadIdx.x;
    const int t   = blockIdx.x * 128 + tid;   // token id

    const int bi = 8191 - (int)(unsigned)(keys[t] & 0xFFFFFFFFull);
    atomicAdd(&counts[bi], 1);

    float4 cr[16];
    const float4* crow = (const float4*)(w + bi * C_DIM);
#pragma unroll
    for (int i = 0; i < 16; ++i) cr[i] = crow[i];
    const float* crs = (const float*)cr;

    const int bb = t >> 10;
    const int hw = t & 1023;
    const float* fb = f + bb * 65536 + hw;
    float*       ob = out + bb * 65536 + hw;

    float s = 0.f;
#pragma unroll
    for (int c = 0; c < C_DIM; ++c) {
        float fv = fb[c * 1024];
        float fh = crs[c];
        float d  = fh - fv;
        s += d * d;
        ob[c * 1024] = fv + d;   // f + sg(fhat - f)
    }

    __shared__ float red[128];
    red[tid] = s;
    __syncthreads();
    for (int st = 64; st > 0; st >>= 1) {
        if (tid < st) red[tid] += red[tid + st];
        __syncthreads();
    }
    if (tid == 0) blocksq[blockIdx.x] = red[0];
}

__global__ __launch_bounds__(256)
void k_stats(const int* __restrict__ counts, const float* __restrict__ blocksq,
             float* __restrict__ out) {
    __shared__ float redf[256];
    __shared__ int   redi[256];
    const int tid = threadIdx.x;
    int used = 0;
    for (int v = tid; v < V_TOTAL; v += 256) used += (counts[v] > 0) ? 1 : 0;
    redi[tid] = used;
    redf[tid] = blocksq[tid];
    __syncthreads();
    for (int st = 128; st > 0; st >>= 1) {
        if (tid < st) { redi[tid] += redi[tid + st]; redf[tid] += redf[tid + st]; }
        __syncthreads();
    }
    if (tid == 0) {
        float mse = redf[0] / 2097152.0f;
        out[2097152] = 0.25f * mse + mse;   // BETA*mean + mean
        out[2097153] = 0.0f;                // entropy_loss
        out[2097154] = 100.0f * (float)redi[0] / 8192.0f;  // vocab_usage
    }
}

extern "C" void kernel_launch(void* const* d_in, const int* in_sizes, int n_in,
                              void* d_out, int out_size, void* d_ws, size_t ws_size,
                              hipStream_t stream) {
    const float* f = (const float*)d_in[0];
    const float* w = (const float*)d_in[1];
    float* out = (float*)d_out;
    float* ws  = (float*)d_ws;

    _Float16*           cp      = (_Float16*)ws;
    unsigned long long* keys    = (unsigned long long*)(ws + 524288);
    int*                counts  = (int*)(ws + 589824);
    float*              blocksq = ws + 598016;

    hipLaunchKernelGGL(k_prep, dim3(32), dim3(256), 0, stream, w, cp, keys, counts);
    hipLaunchKernelGGL(k_argmax, dim3(N_TOK / 128, VSPLIT), dim3(256), 0, stream,
                       f, cp, keys);
    hipLaunchKernelGGL(k_finalize, dim3(N_TOK / 128), dim3(128), 0, stream,
                       f, w, keys, counts, blocksq, out);
    hipLaunchKernelGGL(k_stats, dim3(1), dim3(256), 0, stream,
                       counts, blocksq, out);
}